// Round 1
// baseline (143.050 us; speedup 1.0000x reference)
//
#include <hip/hip_runtime.h>

// Word2Vec negative-sampling scores: out[b][c] = dot(embed[targets[b]], embed[contexts[b][c]])
// B=16384, NCTX=6, E=128, fp32. Memory-bound gather: ~58.7 MB of embedding rows.
//
// Mapping: one 64-lane wave per batch element b.
//   - lane i holds float2 = target row elements [2i, 2i+1]  (512 B coalesced row load)
//   - all 6 context rows loaded up-front (latency overlap)
//   - per-lane partial dot, then 6-step shfl_down tree per context
//   - lane 0 writes the 6 outputs

constexpr int EMBED = 128;
constexpr int NCTX  = 6;

__global__ __launch_bounds__(256) void Word2VecNS_kernel(
    const int*   __restrict__ targets,
    const int*   __restrict__ contexts,
    const float* __restrict__ embed,
    float*       __restrict__ out,
    int batch)
{
    const int wave = (blockIdx.x * blockDim.x + threadIdx.x) >> 6;
    const int lane = threadIdx.x & 63;
    if (wave >= batch) return;

    // Target row fragment: 2 floats per lane (float2, 8 B/lane -> 512 B/row per wave)
    const int t = targets[wave];
    const float2 tv = ((const float2*)(embed + (size_t)t * EMBED))[lane];

    // Context indices (wave-uniform loads -> broadcast)
    int cidx[NCTX];
#pragma unroll
    for (int c = 0; c < NCTX; ++c) cidx[c] = contexts[wave * NCTX + c];

    // Issue all 6 context-row loads before any use (overlap gather latency)
    float2 cv[NCTX];
#pragma unroll
    for (int c = 0; c < NCTX; ++c)
        cv[c] = ((const float2*)(embed + (size_t)cidx[c] * EMBED))[lane];

    // Per-lane partial dots
    float p[NCTX];
#pragma unroll
    for (int c = 0; c < NCTX; ++c)
        p[c] = tv.x * cv[c].x + tv.y * cv[c].y;

    // 64-lane tree reduction (wave = 64 on CDNA)
#pragma unroll
    for (int off = 32; off > 0; off >>= 1) {
#pragma unroll
        for (int c = 0; c < NCTX; ++c)
            p[c] += __shfl_down(p[c], off, 64);
    }

    if (lane == 0) {
        float* o = out + (size_t)wave * NCTX;
#pragma unroll
        for (int c = 0; c < NCTX; ++c) o[c] = p[c];
    }
}

extern "C" void kernel_launch(void* const* d_in, const int* in_sizes, int n_in,
                              void* d_out, int out_size, void* d_ws, size_t ws_size,
                              hipStream_t stream) {
    const int*   targets  = (const int*)d_in[0];
    const int*   contexts = (const int*)d_in[1];
    const float* embed    = (const float*)d_in[2];
    float*       out      = (float*)d_out;

    const int batch = in_sizes[0];           // 16384
    const int waves_per_block = 256 / 64;    // 4
    const int blocks = (batch + waves_per_block - 1) / waves_per_block;

    Word2VecNS_kernel<<<blocks, 256, 0, stream>>>(targets, contexts, embed, out, batch);
}

// Round 2
// 142.015 us; speedup vs baseline: 1.0073x; 1.0073x over previous
//
#include <hip/hip_runtime.h>

// Word2Vec negative-sampling scores: out[b][c] = dot(embed[targets[b]], embed[contexts[b][c]])
// B=16384, NCTX=6, E=128, fp32.
//
// Mapping: one 64-lane wave handles TWO batch elements (one per 32-lane half).
//   - lane: half = lane>>5 selects batch element b = wave*2 + half; sl = lane&31
//   - sl reads float4 = row elements [4*sl .. 4*sl+3]  (32 lanes x 16 B = 512 B row,
//     one load instruction covers 2 rows = 1 KB)
//   - all 6 context-row loads issued up front (7 x 1 KB in flight per wave)
//   - 5-step shfl_xor reduction within each 32-lane half
//   - sl==0 lane of each half writes its 6 outputs

constexpr int EMBED = 128;
constexpr int NCTX  = 6;

__global__ __launch_bounds__(256) void Word2VecNS_kernel(
    const int*   __restrict__ targets,
    const int*   __restrict__ contexts,
    const float* __restrict__ embed,
    float*       __restrict__ out,
    int batch)
{
    const int wave = (blockIdx.x * blockDim.x + threadIdx.x) >> 6;
    const int lane = threadIdx.x & 63;
    const int half = lane >> 5;          // 0 or 1: which batch element this lane serves
    const int sl   = lane & 31;          // sub-lane within the half
    const int b    = wave * 2 + half;
    if (b >= batch) return;              // batch is even; full waves in practice

    // Target row fragment: float4 per lane (16 B x 32 lanes = 512 B row)
    const int t = targets[b];
    const float4 tv = ((const float4*)(embed + (size_t)t * EMBED))[sl];

    // Context indices: 6 ints = 24 B at offset b*24 (8B-aligned) -> 3 x int2
    int cidx[NCTX];
    {
        const int2* cp = (const int2*)(contexts + (size_t)b * NCTX);
        int2 c01 = cp[0], c23 = cp[1], c45 = cp[2];
        cidx[0] = c01.x; cidx[1] = c01.y;
        cidx[2] = c23.x; cidx[3] = c23.y;
        cidx[4] = c45.x; cidx[5] = c45.y;
    }

    // Issue all 6 context-row loads before any use (latency overlap; ~7 KB/wave in flight)
    float4 cv[NCTX];
#pragma unroll
    for (int c = 0; c < NCTX; ++c)
        cv[c] = ((const float4*)(embed + (size_t)cidx[c] * EMBED))[sl];

    // Per-lane partial dots
    float p[NCTX];
#pragma unroll
    for (int c = 0; c < NCTX; ++c)
        p[c] = tv.x * cv[c].x + tv.y * cv[c].y + tv.z * cv[c].z + tv.w * cv[c].w;

    // Butterfly reduction within each 32-lane half (xor offsets < 32 never cross halves)
#pragma unroll
    for (int off = 16; off > 0; off >>= 1) {
#pragma unroll
        for (int c = 0; c < NCTX; ++c)
            p[c] += __shfl_xor(p[c], off, 64);
    }

    if (sl == 0) {
        float* o = out + (size_t)b * NCTX;
#pragma unroll
        for (int c = 0; c < NCTX; ++c) o[c] = p[c];
    }
}

extern "C" void kernel_launch(void* const* d_in, const int* in_sizes, int n_in,
                              void* d_out, int out_size, void* d_ws, size_t ws_size,
                              hipStream_t stream) {
    const int*   targets  = (const int*)d_in[0];
    const int*   contexts = (const int*)d_in[1];
    const float* embed    = (const float*)d_in[2];
    float*       out      = (float*)d_out;

    const int batch = in_sizes[0];                     // 16384
    const int elems_per_block = (256 / 64) * 2;        // 4 waves x 2 elements = 8
    const int blocks = (batch + elems_per_block - 1) / elems_per_block;

    Word2VecNS_kernel<<<blocks, 256, 0, stream>>>(targets, contexts, embed, out, batch);
}